// Round 1
// baseline (1427.585 us; speedup 1.0000x reference)
//
#include <hip/hip_runtime.h>
#include <cstdint>

// Problem constants (from reference)
#define M_ROWS 8192
#define HIDDEN 4096
#define GROUP  128        // fp8 group size == HEAD_DIM
#define NGRP   32         // HIDDEN / GROUP
#define FP8MAX 448.0f
#define EPSV   1e-6f

using float4_t = __attribute__((ext_vector_type(4))) float;

#define BARRIER()    asm volatile("s_barrier" ::: "memory")
#define WAIT_VM4()   asm volatile("s_waitcnt vmcnt(4)" ::: "memory")
#define WAIT_LGKM0() asm volatile("s_waitcnt lgkmcnt(0)" ::: "memory")

// ---------------------------------------------------------------------------
// async global -> LDS, 16 bytes per lane. LDS dest is wave-uniform base +
// lane*16 (global_load_lds constraint); global source may be per-lane.
// ---------------------------------------------------------------------------
__device__ __forceinline__ void async_ld16(const void* g, void* l) {
    __builtin_amdgcn_global_load_lds(
        (const __attribute__((address_space(1))) void*)g,
        (__attribute__((address_space(3))) void*)l, 16, 0, 0);
}

// ---------------------------------------------------------------------------
// Kernel 1: relu(x), relu(z), per-head RMSNorm * norm_weight * silu(z),
// per-(row,head) fp8 e4m3 quantization.
// 32 lanes per head (4 elems/lane, float4 loads); 2 heads per wave.
// a    : [M][HIDDEN] fp8 bytes
// a_sc : [NGRP][M_ROWS] fp32 scales, TRANSPOSED so the GEMM can stage a
//        [kg][row] slice with coalesced loads (keeps gemm vmcnt stream pure).
// ---------------------------------------------------------------------------
__global__ __launch_bounds__(256)
void act_quant_kernel(const float* __restrict__ x, const float* __restrict__ z,
                      const float* __restrict__ nw,
                      uint8_t* __restrict__ a, float* __restrict__ a_sc) {
    const int tid  = threadIdx.x;
    const int lane = tid & 63;
    const int wv   = tid >> 6;
    const int sub  = lane >> 5;       // which of the wave's two heads
    const int l32  = lane & 31;
    const long gh  = (long)blockIdx.x * 8 + wv * 2 + sub;   // head id = row*32+h
    const long row = gh >> 5;
    const int  h   = (int)(gh & 31);
    const long base = row * HIDDEN + (long)h * GROUP + l32 * 4;

    float4_t xv = *(const float4_t*)(x + base);
    float4_t zv = *(const float4_t*)(z + base);
    float xr[4], zr[4];
    float ss = 0.f;
    #pragma unroll
    for (int i = 0; i < 4; ++i) {
        xr[i] = fmaxf(xv[i], 0.f);      // relu
        zr[i] = fmaxf(zv[i], 0.f);      // relu
        ss += xr[i] * xr[i];
    }
    // mean-of-squares over the 128-elem head: butterfly across 32 lanes
    #pragma unroll
    for (int o = 16; o > 0; o >>= 1) ss += __shfl_xor(ss, o, 64);
    const float rstd = 1.0f / sqrtf(ss * (1.0f / 128.0f) + EPSV);

    float4_t w4 = *(const float4_t*)(nw + l32 * 4);
    float g[4], am = 0.f;
    #pragma unroll
    for (int i = 0; i < 4; ++i) {
        // silu(z) = z*sigmoid(z); z >= 0 after relu so exp(-z) is safe
        const float s = zr[i] / (1.f + expf(-zr[i]));
        g[i] = xr[i] * rstd * w4[i] * s;
        am = fmaxf(am, fabsf(g[i]));
    }
    #pragma unroll
    for (int o = 16; o > 0; o >>= 1) am = fmaxf(am, __shfl_xor(am, o, 64));
    const float scale = fmaxf(am, 1e-12f) / FP8MAX;

    int p = __builtin_amdgcn_cvt_pk_fp8_f32(g[0] / scale, g[1] / scale, 0, false);
    p     = __builtin_amdgcn_cvt_pk_fp8_f32(g[2] / scale, g[3] / scale, p, true);
    *(uint32_t*)(a + base) = (uint32_t)p;
    if (l32 == 0) a_sc[(long)h * M_ROWS + row] = scale;
}

// ---------------------------------------------------------------------------
// Kernel 2: per-(128,128)-block fp8 quantization of w.  (unchanged)
// ---------------------------------------------------------------------------
__global__ __launch_bounds__(256)
void w_quant_kernel(const float* __restrict__ w, uint8_t* __restrict__ wq,
                    float* __restrict__ w_sc) {
    const int jb = blockIdx.x, kb = blockIdx.y;
    const int tid  = threadIdx.x;
    const int lane = tid & 63;
    const int wv   = tid >> 6;
    const int r     = tid >> 1;
    const int cbase = (tid & 1) * 64;
    const float* src = w + (long)(jb * 128 + r) * HIDDEN + kb * 128 + cbase;

    float am = 0.f;
    #pragma unroll
    for (int i = 0; i < 16; ++i) {
        float4_t v = *(const float4_t*)(src + i * 4);
        am = fmaxf(am, fmaxf(fmaxf(fabsf(v[0]), fabsf(v[1])),
                             fmaxf(fabsf(v[2]), fabsf(v[3]))));
    }
    #pragma unroll
    for (int o = 32; o > 0; o >>= 1) am = fmaxf(am, __shfl_xor(am, o, 64));

    __shared__ float red[4];
    if (lane == 0) red[wv] = am;
    __syncthreads();
    am = fmaxf(fmaxf(red[0], red[1]), fmaxf(red[2], red[3]));
    const float scale = fmaxf(am, 1e-12f) / FP8MAX;
    if (tid == 0) w_sc[jb * NGRP + kb] = scale;

    uint8_t* dst = wq + (long)(jb * 128 + r) * HIDDEN + kb * 128 + cbase;
    #pragma unroll
    for (int i = 0; i < 16; ++i) {
        float4_t v = *(const float4_t*)(src + i * 4);   // L1/L2-hot re-read
        int p = __builtin_amdgcn_cvt_pk_fp8_f32(v[0] / scale, v[1] / scale, 0, false);
        p     = __builtin_amdgcn_cvt_pk_fp8_f32(v[2] / scale, v[3] / scale, p, true);
        *(uint32_t*)(dst + i * 4) = (uint32_t)p;
    }
}

// ---------------------------------------------------------------------------
// Kernel 3: blockwise-scaled fp8 GEMM, 256x256 tile, 8 waves (2M x 4N),
// K sub-tiles of 64 bytes, ring of 3 LDS buffers, counted-vmcnt pipeline:
//   per sub-tile: 4 phases, each {ds-read quadrant frags | issue 1 staging
//   pass (t+2) -> s_barrier -> 16 MFMA under setprio(1) -> fold scales ->
//   s_barrier}; boundary wait is vmcnt(4) (the 4 in-flight passes of t+2),
//   NEVER vmcnt(0) -- loads span barriers (T3+T4), setprio arbitrates the
//   load-issuing vs MFMA-entering wave split (T5).
// WAR safety: ring slot for tile t+2 was last read in tile t-1; all reads of
// it complete (lgkmcnt before MFMA) before t-1's closing barrier, and t+2's
// stores are issued after that barrier.
// Scales: a-scales staged once into a 32 KiB LDS table (ds_read at fold
// time, lgkmcnt); w-scale read via readfirstlane-forced s_load -- no vector
// global loads inside the main loop, so the vmcnt counting stays exact.
// LDS chunk placement XOR-swizzled at 16B granularity (slot ^ (row&3)):
// linear gload_lds dest + inverse-swizzled global source + swizzled read.
// ---------------------------------------------------------------------------
__global__ __launch_bounds__(512, 2)
void gemm_fp8_scaled(const uint8_t* __restrict__ A, const float* __restrict__ AsT,
                     const uint8_t* __restrict__ B, const float* __restrict__ Ws,
                     float* __restrict__ C) {
    __shared__ uint8_t lA[3][256 * 64];   // 48 KiB ring, A rows
    __shared__ uint8_t lB[3][256 * 64];   // 48 KiB ring, B(=W) rows
    __shared__ float   lSc[NGRP * 256];   // 32 KiB [kg][row] a-scales

    const int tid  = threadIdx.x;
    const int lane = tid & 63;
    const int wv   = tid >> 6;

    // XCD-aware swizzle: nwg = 512 (divisible by 8), bijective
    int wg = blockIdx.x;
    wg = (wg & 7) * 64 + (wg >> 3);
    const long row0 = (long)(wg & 31) * 256;   // 32 M-tiles (fast: B-panel reuse)
    const long col0 = (long)(wg >> 5) * 256;   // 16 N-tiles

    const int m    = lane & 15;
    const int quad = lane >> 4;
    const int wm = (wv & 1) * 128;     // wave's 128-row A strip
    const int wn = (wv >> 1) * 64;     // wave's 64-col  B strip
    const int jb = __builtin_amdgcn_readfirstlane((int)((col0 + wn) >> 7));

    const int sr  = tid >> 2;          // staging row 0..127 per pass
    const int sc  = tid & 3;           // 16B chunk slot within 64B row
    const int scs = sc ^ (sr & 3);     // inverse-swizzled source chunk

    auto stage = [&](int t2, int slot, int q) {
        const long kof = (long)t2 * 64 + scs * 16;
        if (q < 2)
            async_ld16(A + (row0 + q * 128 + sr) * HIDDEN + kof,
                       &lA[slot][q * 8192 + tid * 16]);
        else
            async_ld16(B + (col0 + (q - 2) * 128 + sr) * HIDDEN + kof,
                       &lB[slot][(q - 2) * 8192 + tid * 16]);
    };

    // prologue: scale table + sub-tiles 0,1; vmcnt(4) leaves tile1 in flight
    for (int i = tid; i < NGRP * 256; i += 512)
        lSc[i] = AsT[(long)(i >> 8) * M_ROWS + row0 + (i & 255)];
    #pragma unroll
    for (int q = 0; q < 4; ++q) stage(0, 0, q);
    #pragma unroll
    for (int q = 0; q < 4; ++q) stage(1, 1, q);
    WAIT_VM4();
    WAIT_LGKM0();
    BARRIER();

    float4_t acc[8][4] = {};
    long bv[4][2];
    float wsc = 0.f;

    for (int t = 0; t < HIDDEN / 64; ++t) {
        const int cur = t % 3;
        const int g   = t >> 1;                    // 128-wide scale group
        if ((t & 1) == 0) wsc = Ws[jb * NGRP + g]; // uniform -> s_load
        const uint8_t* bufA = lA[cur];
        const uint8_t* bufB = lB[cur];
        #pragma unroll
        for (int q = 0; q < 4; ++q) {
            // ---- ds-read this phase's fragments (swizzled) ----
            long av[2][2];
            #pragma unroll
            for (int i2 = 0; i2 < 2; ++i2) {
                const int r = wm + (2 * q + i2) * 16 + m;
                #pragma unroll
                for (int ks = 0; ks < 2; ++ks) {
                    const int ci = ks * 2 + (quad >> 1);
                    av[i2][ks] = *(const long*)&bufA[r * 64 +
                        ((ci ^ (r & 3)) * 16) + (quad & 1) * 8];
                }
            }
            if (q == 0) {   // B frags cached in regs across the 4 phases
                #pragma unroll
                for (int nt = 0; nt < 4; ++nt) {
                    const int r = wn + nt * 16 + m;
                    #pragma unroll
                    for (int ks = 0; ks < 2; ++ks) {
                        const int ci = ks * 2 + (quad >> 1);
                        bv[nt][ks] = *(const long*)&bufB[r * 64 +
                            ((ci ^ (r & 3)) * 16) + (quad & 1) * 8];
                    }
                }
            }
            float4_t s4[2];
            #pragma unroll
            for (int i2 = 0; i2 < 2; ++i2)
                s4[i2] = *(const float4_t*)&lSc[g * 256 + wm +
                                                (2 * q + i2) * 16 + quad * 4];

            // ---- issue one staging pass for sub-tile t+2 ----
            if (t + 2 < HIDDEN / 64) stage(t + 2, (t + 2) % 3, q);
            if (q == 3) WAIT_VM4();    // tile t+1 fully landed; t+2 in flight
            BARRIER();

            // ---- MFMA cluster ----
            __builtin_amdgcn_s_setprio(1);
            float4_t part[2][4] = {};
            #pragma unroll
            for (int ks = 0; ks < 2; ++ks)
                #pragma unroll
                for (int i2 = 0; i2 < 2; ++i2)
                    #pragma unroll
                    for (int nt = 0; nt < 4; ++nt)
                        part[i2][nt] = __builtin_amdgcn_mfma_f32_16x16x32_fp8_fp8(
                            av[i2][ks], bv[nt][ks], part[i2][nt], 0, 0, 0);
            __builtin_amdgcn_s_setprio(0);

            // ---- fold group scales: acc += (a_sc*w_sc) * part ----
            #pragma unroll
            for (int i2 = 0; i2 < 2; ++i2) {
                const float s0 = s4[i2][0] * wsc, s1 = s4[i2][1] * wsc;
                const float s2 = s4[i2][2] * wsc, s3 = s4[i2][3] * wsc;
                #pragma unroll
                for (int nt = 0; nt < 4; ++nt) {
                    acc[2 * q + i2][nt][0] += s0 * part[i2][nt][0];
                    acc[2 * q + i2][nt][1] += s1 * part[i2][nt][1];
                    acc[2 * q + i2][nt][2] += s2 * part[i2][nt][2];
                    acc[2 * q + i2][nt][3] += s3 * part[i2][nt][3];
                }
            }
            BARRIER();
        }
    }

    // ---- epilogue: C/D layout col=lane&15, row=quad*4+reg ----
    #pragma unroll
    for (int mt = 0; mt < 8; ++mt)
        #pragma unroll
        for (int nt = 0; nt < 4; ++nt) {
            const long r  = row0 + wm + mt * 16 + quad * 4;
            const long cc = col0 + wn + nt * 16 + m;
            #pragma unroll
            for (int gg = 0; gg < 4; ++gg)
                C[(r + gg) * HIDDEN + cc] = acc[mt][nt][gg];
        }
}

// ---------------------------------------------------------------------------
extern "C" void kernel_launch(void* const* d_in, const int* in_sizes, int n_in,
                              void* d_out, int out_size, void* d_ws, size_t ws_size,
                              hipStream_t stream) {
    const float* x  = (const float*)d_in[0];
    const float* z  = (const float*)d_in[1];
    const float* nw = (const float*)d_in[2];
    const float* w  = (const float*)d_in[3];
    float* out = (float*)d_out;

    // workspace layout (~49.3 MB)
    uint8_t* ws8   = (uint8_t*)d_ws;
    uint8_t* a_fp8 = ws8;                                   // 8192*4096 = 32 MiB
    uint8_t* w_fp8 = ws8 + (size_t)M_ROWS * HIDDEN;         // 4096*4096 = 16 MiB
    float*   a_sc  = (float*)(w_fp8 + (size_t)HIDDEN * HIDDEN); // [NGRP][M] 1 MiB
    float*   w_sc  = a_sc + (size_t)M_ROWS * NGRP;              // 4 KiB

    act_quant_kernel<<<M_ROWS * NGRP / 8, 256, 0, stream>>>(x, z, nw, a_fp8, a_sc);
    w_quant_kernel<<<dim3(NGRP, NGRP), 256, 0, stream>>>(w, w_fp8, w_sc);
    gemm_fp8_scaled<<<M_ROWS / 256 * (HIDDEN / 256), 512, 0, stream>>>(
        a_fp8, a_sc, w_fp8, w_sc, out);
}